// Round 1
// baseline (303.250 us; speedup 1.0000x reference)
//
#include <hip/hip_runtime.h>

typedef __attribute__((ext_vector_type(8))) short short8;
typedef __attribute__((ext_vector_type(4))) float f32x4;

// ws layout (bytes)
#define WFT_OFF 0          // bf16[256*512]          = 262144 B
#define HB_OFF  262144     // f32[32*256]            =  32768 B
#define SC_OFF  294912     // f32[131072] scores     = 524288 B
#define ST_OFF  819200     // f32[2048*2] m,l        =  16384 B
#define CP_OFF  835584     // f32[2048*512] ctx part = 4194304 B  (total ~4.8 MB)

// LDS: Ab [64][512] bf16 swizzled (64 KB) @0
//      Bb double buffer 2x [256][64] bf16 swizzled (2x32 KB) @65536 / @98304
//      epilogue aliases into buf0: scratch f32[8][512] @65536, wpart f32[4][64] @81920, wbuf f32[64] @82944
#define SMEM_MAIN 131072

__device__ __forceinline__ unsigned short f2bf(float f) {
    unsigned u = __builtin_bit_cast(unsigned, f);
    u += 0x7fffu + ((u >> 16) & 1u);
    return (unsigned short)(u >> 16);
}
__device__ __forceinline__ float bf2f(unsigned short h) {
    unsigned u = ((unsigned)h) << 16;
    return __builtin_bit_cast(float, u);
}
__device__ __forceinline__ float fast_tanh(float x) {
    float e2 = __expf(2.0f * x);
    return 1.0f - 2.0f / (e2 + 1.0f);
}
// LDS-only barrier: does NOT drain vmcnt, so the global-load burst stays in flight.
__device__ __forceinline__ void lds_barrier() {
    asm volatile("s_waitcnt lgkmcnt(0)" ::: "memory");
    __builtin_amdgcn_s_barrier();
}

// ---- Wf (512x256 f32) -> WfT (256x512 bf16), tiled transpose ----
__global__ void wft_kernel(const float* __restrict__ Wf, unsigned short* __restrict__ WfT) {
    __shared__ unsigned short tl[64 * 80];
    const int t = threadIdx.x;
    const int tk = blockIdx.x >> 2, ta = blockIdx.x & 3;
    const int d0 = tk * 64, a0 = ta * 64;
#pragma unroll
    for (int i = 0; i < 16; ++i) {
        int flat = t + 256 * i;
        int dl = flat >> 6, al = flat & 63;
        tl[al * 80 + dl] = f2bf(Wf[(d0 + dl) * 256 + a0 + al]);
    }
    __syncthreads();
#pragma unroll
    for (int i = 0; i < 2; ++i) {
        int u = t + 256 * i;
        int al = u >> 3, q = u & 7;
        *(uint4*)(&WfT[(size_t)(a0 + al) * 512 + d0 + q * 8]) =
            *(const uint4*)(&tl[al * 80 + q * 8]);
    }
}

// ---- hb[b][a] = hidden[b]·Wh[:,a] + bh[a] + bf[a] ----
__global__ void hb_kernel(const float* __restrict__ hidden, const float* __restrict__ Wh,
                          const float* __restrict__ bh, const float* __restrict__ bfv,
                          float* __restrict__ hb) {
    const int b = blockIdx.x, a = threadIdx.x;
    float acc = bh[a] + bfv[a];
    const float* hrow = hidden + b * 512;
#pragma unroll 8
    for (int d = 0; d < 512; ++d)
        acc += hrow[d] * Wh[d * 256 + a];
    hb[b * 256 + a] = acc;
}

// ---- persistent fused kernel: 256 blocks x 8 tiles each ----
__launch_bounds__(512, 2)
__global__ void main_kernel(const float* __restrict__ feats,
                            const unsigned short* __restrict__ WfT,
                            const float* __restrict__ hbg,
                            const float* __restrict__ Ws,
                            float* __restrict__ scores,
                            float* __restrict__ stats,
                            float* __restrict__ ctxp) {
    extern __shared__ char smem[];
    char* Ab = smem;                            // [64][512] bf16 swizzled
    float* scratch = (float*)(smem + 65536);    // [8][512] f32 (aliases B buf0)
    float* wpart   = (float*)(smem + 81920);    // [4][64]
    float* wbuf    = (float*)(smem + 82944);    // [64]

    const int t = threadIdx.x;
    const int lane = t & 63, wv = t >> 6;
    const int wr = wv >> 2, wc = wv & 3;        // wave: 32 rows x 64 cols
    const int lr = lane & 15, lg = lane >> 4;
    const int swz = (lr & 7) << 4;

    const int arow_s = t >> 4;                  // A rows: arow_s and arow_s+32
    const int ac4 = t & 15;

    float4 areg[2][8];                          // full-tile A burst (64 VGPRs)
    uint4 breg[4];

    // prologue burst: tile = blockIdx.x
    {
        const float4* fp = (const float4*)feats + (size_t)blockIdx.x * 64 * 128;
#pragma unroll
        for (int kc = 0; kc < 8; ++kc) {
            areg[0][kc] = fp[(size_t)arow_s * 128 + kc * 16 + ac4];
            areg[1][kc] = fp[(size_t)(arow_s + 32) * 128 + kc * 16 + ac4];
        }
    }

    for (int it = 0; it < 8; ++it) {
        const int tile = blockIdx.x + it * 256;
        const int b = tile >> 6;

        // epilogue operands: issued EARLIEST so no later wait entangles them
        float hbv[4], wsv[4];
#pragma unroll
        for (int j = 0; j < 4; ++j) {
            int col = wc * 64 + j * 16 + lr;
            hbv[j] = hbg[b * 256 + col];
            wsv[j] = Ws[col];
        }
        // B chunk 0 (before any burst parts of this tile)
#pragma unroll
        for (int i = 0; i < 4; ++i) {
            int flat = t + 512 * i;
            int br = flat >> 3, q = flat & 7;
            breg[i] = *(const uint4*)(WfT + (size_t)br * 512 + q * 8);
        }

        if (it > 0) lds_barrier();              // prev tile done with Ab + aliased buffers

        // store whole A tile (waits areg burst progressively via register deps)
#pragma unroll
        for (int kc = 0; kc < 8; ++kc) {
#pragma unroll
            for (int h = 0; h < 2; ++h) {
                int row = arow_s + h * 32;
                int kbyte = kc * 128 + ac4 * 8;
                float4 v = areg[h][kc];
                uint2 u;
                u.x = (unsigned)f2bf(v.x) | ((unsigned)f2bf(v.y) << 16);
                u.y = (unsigned)f2bf(v.z) | ((unsigned)f2bf(v.w) << 16);
                *(uint2*)(Ab + row * 1024 + (kbyte ^ ((row & 7) << 4))) = u;
            }
        }

        const float4* fnext = (const float4*)feats +
                              (size_t)(it < 7 ? tile + 256 : tile) * 64 * 128;

        f32x4 acc[2][4] = {};

#pragma unroll
        for (int kc = 0; kc < 8; ++kc) {
            char* Bb = smem + 65536 + ((kc & 1) << 15);   // double buffer
            // store B chunk kc
#pragma unroll
            for (int i = 0; i < 4; ++i) {
                int flat = t + 512 * i;
                int br = flat >> 3, q = flat & 7;
                *(uint4*)(Bb + br * 128 + ((q * 16) ^ ((br & 7) << 4))) = breg[i];
            }
            // prefetch B chunk kc+1 (BEFORE burst parts: its wait stays vmcnt(2))
            if (kc < 7) {
#pragma unroll
                for (int i = 0; i < 4; ++i) {
                    int flat = t + 512 * i;
                    int br = flat >> 3, q = flat & 7;
                    breg[i] = *(const uint4*)(WfT + (size_t)br * 512 + (kc + 1) * 64 + q * 8);
                }
            }
            // stream next tile's A: 2 loads/chunk keeps the HBM queue deep all tile long
            if (it < 7) {
                areg[0][kc] = fnext[(size_t)arow_s * 128 + kc * 16 + ac4];
                areg[1][kc] = fnext[(size_t)(arow_s + 32) * 128 + kc * 16 + ac4];
            }
            lds_barrier();                      // B chunk visible (and A tile on kc==0); vmcnt untouched
            // GEMM chunk kc
#pragma unroll
            for (int ks = 0; ks < 2; ++ks) {
                int kb = (ks * 32 + lg * 8) * 2;
                short8 af[2], bf4[4];
#pragma unroll
                for (int i = 0; i < 2; ++i) {
                    int row = wr * 32 + i * 16 + lr;
                    af[i] = *(const short8*)(Ab + row * 1024 + ((kc * 128 + kb) ^ swz));
                }
#pragma unroll
                for (int j = 0; j < 4; ++j) {
                    int col = wc * 64 + j * 16 + lr;
                    bf4[j] = *(const short8*)(Bb + col * 128 + (kb ^ swz));
                }
#pragma unroll
                for (int i = 0; i < 2; ++i)
#pragma unroll
                    for (int j = 0; j < 4; ++j)
                        acc[i][j] = __builtin_amdgcn_mfma_f32_16x16x32_bf16(af[i], bf4[j], acc[i][j], 0, 0, 0);
            }
        }

        // epilogue: scores = sum_a tanh(C + hb[a]) * Ws[a]
        // wpart/wbuf live in B buf0; last GEMM read buf1 -> no race before the barrier below
#pragma unroll
        for (int i = 0; i < 2; ++i) {
#pragma unroll
            for (int r = 0; r < 4; ++r) {
                float p = 0.f;
#pragma unroll
                for (int j = 0; j < 4; ++j) {
                    float e = fast_tanh(acc[i][j][r] + hbv[j]);
                    p += e * wsv[j];
                }
#pragma unroll
                for (int off = 1; off < 16; off <<= 1) p += __shfl_xor(p, off, 64);
                if (lr == 0) wpart[wc * 64 + wr * 32 + i * 16 + lg * 4 + r] = p;
            }
        }
        lds_barrier();

        // block softmax stats (wave 0)
        if (t < 64) {
            float s = wpart[t] + wpart[64 + t] + wpart[128 + t] + wpart[192 + t];
            scores[tile * 64 + t] = s;
            float m = s;
#pragma unroll
            for (int off = 1; off < 64; off <<= 1) m = fmaxf(m, __shfl_xor(m, off, 64));
            float e = __expf(s - m);
            float l = e;
#pragma unroll
            for (int off = 1; off < 64; off <<= 1) l += __shfl_xor(l, off, 64);
            wbuf[t] = e;
            if (t == 0) { stats[tile * 2] = m; stats[tile * 2 + 1] = l; }
        }
        lds_barrier();

        // ctx partial from LDS-resident bf16 A tile
        {
            float accd[8] = {};
            const int nset = t >> 6, dg = t & 63;
            const int d0 = dg * 8;
#pragma unroll
            for (int nn = 0; nn < 8; ++nn) {
                int n = nset * 8 + nn;
                float w = wbuf[n];
                short8 av = *(const short8*)(Ab + n * 1024 + ((d0 * 2) ^ ((n & 7) << 4)));
#pragma unroll
                for (int e = 0; e < 8; ++e)
                    accd[e] += w * bf2f((unsigned short)av[e]);
            }
            float4 v0, v1;
            v0.x = accd[0]; v0.y = accd[1]; v0.z = accd[2]; v0.w = accd[3];
            v1.x = accd[4]; v1.y = accd[5]; v1.z = accd[6]; v1.w = accd[7];
            *(float4*)(scratch + nset * 512 + d0) = v0;
            *(float4*)(scratch + nset * 512 + d0 + 4) = v1;
        }
        lds_barrier();
        {
            float s = 0.f;
#pragma unroll
            for (int ns = 0; ns < 8; ++ns) s += scratch[ns * 512 + t];
            ctxp[(size_t)tile * 512 + t] = s;
        }
    }
}

// ---- per-batch: global softmax + alpha + ctx merge ----
__global__ void combine_kernel(const float* __restrict__ scores,
                               const float* __restrict__ stats,
                               const float* __restrict__ ctxp,
                               float* __restrict__ out_ctx,
                               float* __restrict__ out_alpha) {
    __shared__ float scales[64];
    __shared__ float MZ[2];
    const int b = blockIdx.x, t = threadIdx.x;
    if (t < 64) {
        float mk = stats[(b * 64 + t) * 2];
        float lk = stats[(b * 64 + t) * 2 + 1];
        float M = mk;
#pragma unroll
        for (int off = 1; off < 64; off <<= 1) M = fmaxf(M, __shfl_xor(M, off, 64));
        float e = __expf(mk - M);
        float z = lk * e;
#pragma unroll
        for (int off = 1; off < 64; off <<= 1) z += __shfl_xor(z, off, 64);
        scales[t] = e / z;
        if (t == 0) { MZ[0] = M; MZ[1] = z; }
    }
    __syncthreads();
    const float M = MZ[0], invZ = 1.0f / MZ[1];
    const float* sb = scores + b * 4096;
    float* abp = out_alpha + b * 4096;
#pragma unroll
    for (int i = 0; i < 16; ++i) {
        int n = t + 256 * i;
        abp[n] = __expf(sb[n] - M) * invZ;
    }
    const int d0 = t * 2;
    float2 acc; acc.x = 0.f; acc.y = 0.f;
    for (int k = 0; k < 64; ++k) {
        float sc = scales[k];
        const float2 v = *(const float2*)(ctxp + ((size_t)(b * 64 + k) * 512 + d0));
        acc.x += sc * v.x; acc.y += sc * v.y;
    }
    *(float2*)(out_ctx + b * 512 + d0) = acc;
}

extern "C" void kernel_launch(void* const* d_in, const int* in_sizes, int n_in,
                              void* d_out, int out_size, void* d_ws, size_t ws_size,
                              hipStream_t stream) {
    (void)in_sizes; (void)n_in; (void)out_size; (void)ws_size;
    const float* feats  = (const float*)d_in[0];
    const float* hidden = (const float*)d_in[1];
    const float* Wf     = (const float*)d_in[2];
    const float* bfv    = (const float*)d_in[3];
    const float* Wh     = (const float*)d_in[4];
    const float* bh     = (const float*)d_in[5];
    const float* Ws     = (const float*)d_in[6];
    // d_in[7] (bs) irrelevant: softmax is shift-invariant and scores are not output.

    char* ws = (char*)d_ws;
    unsigned short* WfT = (unsigned short*)(ws + WFT_OFF);
    float* hb     = (float*)(ws + HB_OFF);
    float* scores = (float*)(ws + SC_OFF);
    float* stats  = (float*)(ws + ST_OFF);
    float* ctxp   = (float*)(ws + CP_OFF);

    float* out_ctx   = (float*)d_out;
    float* out_alpha = out_ctx + 32 * 512;

    hipFuncSetAttribute((const void*)main_kernel,
                        hipFuncAttributeMaxDynamicSharedMemorySize, SMEM_MAIN);

    hipLaunchKernelGGL(wft_kernel, dim3(32), dim3(256), 0, stream, Wf, WfT);
    hipLaunchKernelGGL(hb_kernel, dim3(32), dim3(256), 0, stream, hidden, Wh, bh, bfv, hb);
    hipLaunchKernelGGL(main_kernel, dim3(256), dim3(512), SMEM_MAIN, stream,
                       feats, WfT, hb, Ws, scores, stats, ctxp);
    hipLaunchKernelGGL(combine_kernel, dim3(32), dim3(256), 0, stream,
                       scores, stats, ctxp, out_ctx, out_alpha);
}

// Round 2
// 141.959 us; speedup vs baseline: 2.1362x; 2.1362x over previous
//
#include <hip/hip_runtime.h>

typedef __attribute__((ext_vector_type(8))) short short8;
typedef __attribute__((ext_vector_type(4))) float f32x4;

// ws layout (bytes) — unchanged from round 0
#define WFT_OFF 0          // bf16[256*512]          = 262144 B
#define HB_OFF  262144     // f32[32*256]            =  32768 B
#define SC_OFF  294912     // f32[131072] scores     = 524288 B
#define ST_OFF  819200     // f32[2048*2] m,l        =  16384 B
#define CP_OFF  835584     // f32[2048*512] ctx part = 4194304 B

// LDS per block (76 KB -> 2 blocks/CU on 160 KB):
//   Ab      [64][512] bf16 swizzled   @0      (65536 B)
//   scratch [4][512]  f32             @65536  ( 8192 B)
//   wpart   [8][64]   f32             @73728  ( 2048 B)
//   wbuf    [64]      f32             @75776  (  256 B)
#define SMEM_MAIN 76032

__device__ __forceinline__ unsigned short f2bf(float f) {
    unsigned u = __builtin_bit_cast(unsigned, f);
    u += 0x7fffu + ((u >> 16) & 1u);
    return (unsigned short)(u >> 16);
}
__device__ __forceinline__ float bf2f(unsigned short h) {
    unsigned u = ((unsigned)h) << 16;
    return __builtin_bit_cast(float, u);
}
__device__ __forceinline__ float fast_tanh(float x) {
    float e2 = __expf(2.0f * x);
    return 1.0f - 2.0f / (e2 + 1.0f);
}
// LDS-only barrier: no vmcnt drain (only LDS data crosses block barriers here).
__device__ __forceinline__ void lds_barrier() {
    asm volatile("s_waitcnt lgkmcnt(0)" ::: "memory");
    __builtin_amdgcn_s_barrier();
}

// ---- Wf (512x256 f32) -> WfT (256x512 bf16), tiled transpose ----
__global__ void wft_kernel(const float* __restrict__ Wf, unsigned short* __restrict__ WfT) {
    __shared__ unsigned short tl[64 * 80];
    const int t = threadIdx.x;
    const int tk = blockIdx.x >> 2, ta = blockIdx.x & 3;
    const int d0 = tk * 64, a0 = ta * 64;
#pragma unroll
    for (int i = 0; i < 16; ++i) {
        int flat = t + 256 * i;
        int dl = flat >> 6, al = flat & 63;
        tl[al * 80 + dl] = f2bf(Wf[(d0 + dl) * 256 + a0 + al]);
    }
    __syncthreads();
#pragma unroll
    for (int i = 0; i < 2; ++i) {
        int u = t + 256 * i;
        int al = u >> 3, q = u & 7;
        *(uint4*)(&WfT[(size_t)(a0 + al) * 512 + d0 + q * 8]) =
            *(const uint4*)(&tl[al * 80 + q * 8]);
    }
}

// ---- hb[b][a] = hidden[b]·Wh[:,a] + bh[a] + bf[a] ----
__global__ void hb_kernel(const float* __restrict__ hidden, const float* __restrict__ Wh,
                          const float* __restrict__ bh, const float* __restrict__ bfv,
                          float* __restrict__ hb) {
    const int b = blockIdx.x, a = threadIdx.x;
    float acc = bh[a] + bfv[a];
    const float* hrow = hidden + b * 512;
#pragma unroll 8
    for (int d = 0; d < 512; ++d)
        acc += hrow[d] * Wh[d * 256 + a];
    hb[b * 256 + a] = acc;
}

// ---- fused: scores GEMM (B direct from L2) + tanh·Ws + block stats + ctx partial ----
// 2048 blocks x 512 thr, 76 KB LDS -> 2 blocks/CU, 4 waves/SIMD.
// GEMM loop has ZERO barriers: A is read-only LDS after one stage barrier,
// B fragments stream straight from L2-resident WfT with a register double-buffer.
__launch_bounds__(512, 4)
__global__ void main_kernel(const float* __restrict__ feats,
                            const unsigned short* __restrict__ WfT,
                            const float* __restrict__ hbg,
                            const float* __restrict__ Ws,
                            float* __restrict__ scores,
                            float* __restrict__ stats,
                            float* __restrict__ ctxp) {
    extern __shared__ char smem[];
    char* Ab       = smem;                      // [64][1024 B] bf16, XOR-swizzled rows
    float* scratch = (float*)(smem + 65536);    // [4][512]
    float* wpart   = (float*)(smem + 73728);    // [8][64]
    float* wbuf    = (float*)(smem + 75776);    // [64]

    const int t = threadIdx.x;
    const int tile = blockIdx.x;
    const int b = tile >> 6;
    const int row0 = tile * 64;
    const int lane = t & 63, w = t >> 6;        // 8 waves; wave w owns cols w*32..w*32+31
    const int lr = lane & 15, lg = lane >> 4;
    const int sw = (lr & 7) << 4;

    // ---- stage A tile: feats f32 -> bf16 LDS (one barrier total) ----
    {
        const int ar = t >> 3;                  // row 0..63 (8 threads/row)
        const int c8 = t & 7;
        const float4* fr = (const float4*)(feats + (size_t)(row0 + ar) * 512);
        char* arow = Ab + ar * 1024;
        const int rsw = (ar & 7) << 4;
#pragma unroll
        for (int i = 0; i < 16; ++i) {
            int f4 = c8 + i * 8;                // float4 index 0..127 within row
            float4 v = fr[f4];
            uint2 u;
            u.x = (unsigned)f2bf(v.x) | ((unsigned)f2bf(v.y) << 16);
            u.y = (unsigned)f2bf(v.z) | ((unsigned)f2bf(v.w) << 16);
            *(uint2*)(arow + ((f4 * 8) ^ rsw)) = u;
        }
    }

    // epilogue operands straight from global (L2-hit, no LDS)
    float hbv[2], wsv[2];
#pragma unroll
    for (int j = 0; j < 2; ++j) {
        int col = w * 32 + j * 16 + lr;
        hbv[j] = hbg[b * 256 + col];
        wsv[j] = Ws[col];
    }

    lds_barrier();                              // A tile staged

    // ---- GEMM 64x256x512: per wave 64 rows x 32 cols, K chunks of 32 ----
    f32x4 acc[4][2] = {};
    const unsigned short* bp0 = WfT + (size_t)(w * 32 + lr) * 512 + lg * 8;
    const unsigned short* bp1 = WfT + (size_t)(w * 32 + 16 + lr) * 512 + lg * 8;

    uint4 bfr[2][2];                            // [buf][j] — indices compile-time under unroll
    bfr[0][0] = *(const uint4*)(bp0);
    bfr[0][1] = *(const uint4*)(bp1);
#pragma unroll
    for (int ks = 0; ks < 16; ++ks) {
        const int cur = ks & 1, nxt = cur ^ 1;
        if (ks < 15) {                          // prefetch next K-chunk's B frags (L2)
            bfr[nxt][0] = *(const uint4*)(bp0 + (ks + 1) * 32);
            bfr[nxt][1] = *(const uint4*)(bp1 + (ks + 1) * 32);
        }
        short8 af[4];
#pragma unroll
        for (int i = 0; i < 4; ++i) {
            int row = i * 16 + lr;
            af[i] = *(const short8*)(Ab + row * 1024 + ((ks * 64 + lg * 16) ^ sw));
        }
        short8 b0 = __builtin_bit_cast(short8, bfr[cur][0]);
        short8 b1 = __builtin_bit_cast(short8, bfr[cur][1]);
#pragma unroll
        for (int i = 0; i < 4; ++i) {
            acc[i][0] = __builtin_amdgcn_mfma_f32_16x16x32_bf16(af[i], b0, acc[i][0], 0, 0, 0);
            acc[i][1] = __builtin_amdgcn_mfma_f32_16x16x32_bf16(af[i], b1, acc[i][1], 0, 0, 0);
        }
    }

    // ---- epilogue: scores = sum_a tanh(C + hb[a]) * Ws[a] ----
    // C frag: col = lr (within j-frag), row = i*16 + lg*4 + r
#pragma unroll
    for (int i = 0; i < 4; ++i) {
#pragma unroll
        for (int r = 0; r < 4; ++r) {
            float p = fast_tanh(acc[i][0][r] + hbv[0]) * wsv[0]
                    + fast_tanh(acc[i][1][r] + hbv[1]) * wsv[1];
#pragma unroll
            for (int off = 1; off < 16; off <<= 1) p += __shfl_xor(p, off, 64);
            if (lr == 0) wpart[w * 64 + i * 16 + lg * 4 + r] = p;
        }
    }
    lds_barrier();

    // block softmax stats (wave 0 only)
    if (t < 64) {
        float s = 0.f;
#pragma unroll
        for (int k = 0; k < 8; ++k) s += wpart[k * 64 + t];
        scores[row0 + t] = s;
        float m = s;
#pragma unroll
        for (int off = 1; off < 64; off <<= 1) m = fmaxf(m, __shfl_xor(m, off, 64));
        float e = __expf(s - m);
        float l = e;
#pragma unroll
        for (int off = 1; off < 64; off <<= 1) l += __shfl_xor(l, off, 64);
        wbuf[t] = e;
        if (t == 0) { stats[tile * 2] = m; stats[tile * 2 + 1] = l; }
    }
    lds_barrier();

    // ---- ctx partial from LDS-resident bf16 A tile ----
    {
        const int nset = t >> 7;                // 4 sets x 16 rows
        const int dt = t & 127;                 // 128 threads x 4 d-cols = 512
        float accd[4] = {};
#pragma unroll
        for (int nn = 0; nn < 16; ++nn) {
            int n = nset * 16 + nn;
            float wv = wbuf[n];
            unsigned long long a8 =
                *(const unsigned long long*)(Ab + n * 1024 + ((dt * 8) ^ ((n & 7) << 4)));
            accd[0] += wv * bf2f((unsigned short)(a8));
            accd[1] += wv * bf2f((unsigned short)(a8 >> 16));
            accd[2] += wv * bf2f((unsigned short)(a8 >> 32));
            accd[3] += wv * bf2f((unsigned short)(a8 >> 48));
        }
        float4 v;
        v.x = accd[0]; v.y = accd[1]; v.z = accd[2]; v.w = accd[3];
        *(float4*)(scratch + nset * 512 + dt * 4) = v;
    }
    lds_barrier();
    {
        float s = scratch[t] + scratch[512 + t] + scratch[1024 + t] + scratch[1536 + t];
        ctxp[(size_t)tile * 512 + t] = s;
    }
}

// ---- per-batch: global softmax + alpha + ctx merge ----
__global__ void combine_kernel(const float* __restrict__ scores,
                               const float* __restrict__ stats,
                               const float* __restrict__ ctxp,
                               float* __restrict__ out_ctx,
                               float* __restrict__ out_alpha) {
    __shared__ float scales[64];
    __shared__ float MZ[2];
    const int b = blockIdx.x, t = threadIdx.x;
    if (t < 64) {
        float mk = stats[(b * 64 + t) * 2];
        float lk = stats[(b * 64 + t) * 2 + 1];
        float M = mk;
#pragma unroll
        for (int off = 1; off < 64; off <<= 1) M = fmaxf(M, __shfl_xor(M, off, 64));
        float e = __expf(mk - M);
        float z = lk * e;
#pragma unroll
        for (int off = 1; off < 64; off <<= 1) z += __shfl_xor(z, off, 64);
        scales[t] = e / z;
        if (t == 0) { MZ[0] = M; MZ[1] = z; }
    }
    __syncthreads();
    const float M = MZ[0], invZ = 1.0f / MZ[1];
    const float* sb = scores + b * 4096;
    float* abp = out_alpha + b * 4096;
#pragma unroll
    for (int i = 0; i < 16; ++i) {
        int n = t + 256 * i;
        abp[n] = __expf(sb[n] - M) * invZ;
    }
    const int d0 = t * 2;
    float2 acc; acc.x = 0.f; acc.y = 0.f;
    for (int k = 0; k < 64; ++k) {
        float sc = scales[k];
        const float2 v = *(const float2*)(ctxp + ((size_t)(b * 64 + k) * 512 + d0));
        acc.x += sc * v.x; acc.y += sc * v.y;
    }
    *(float2*)(out_ctx + b * 512 + d0) = acc;
}

extern "C" void kernel_launch(void* const* d_in, const int* in_sizes, int n_in,
                              void* d_out, int out_size, void* d_ws, size_t ws_size,
                              hipStream_t stream) {
    (void)in_sizes; (void)n_in; (void)out_size; (void)ws_size;
    const float* feats  = (const float*)d_in[0];
    const float* hidden = (const float*)d_in[1];
    const float* Wf     = (const float*)d_in[2];
    const float* bfv    = (const float*)d_in[3];
    const float* Wh     = (const float*)d_in[4];
    const float* bh     = (const float*)d_in[5];
    const float* Ws     = (const float*)d_in[6];
    // d_in[7] (bs) irrelevant: softmax is shift-invariant and scores are not output.

    char* ws = (char*)d_ws;
    unsigned short* WfT = (unsigned short*)(ws + WFT_OFF);
    float* hb     = (float*)(ws + HB_OFF);
    float* scores = (float*)(ws + SC_OFF);
    float* stats  = (float*)(ws + ST_OFF);
    float* ctxp   = (float*)(ws + CP_OFF);

    float* out_ctx   = (float*)d_out;
    float* out_alpha = out_ctx + 32 * 512;

    hipFuncSetAttribute((const void*)main_kernel,
                        hipFuncAttributeMaxDynamicSharedMemorySize, SMEM_MAIN);

    hipLaunchKernelGGL(wft_kernel, dim3(32), dim3(256), 0, stream, Wf, WfT);
    hipLaunchKernelGGL(hb_kernel, dim3(32), dim3(256), 0, stream, hidden, Wh, bh, bfv, hb);
    hipLaunchKernelGGL(main_kernel, dim3(2048), dim3(512), SMEM_MAIN, stream,
                       feats, WfT, hb, Ws, scores, stats, ctxp);
    hipLaunchKernelGGL(combine_kernel, dim3(32), dim3(256), 0, stream,
                       scores, stats, ctxp, out_ctx, out_alpha);
}